// Round 11
// baseline (394.065 us; speedup 1.0000x reference)
//
#include <hip/hip_runtime.h>

#define S_DIM 4096
#define C_IN  256
#define E_DIM 512
#define HD    64
#define EPSV  1e-5f

typedef __attribute__((ext_vector_type(8))) short s8v;
typedef __attribute__((ext_vector_type(4))) short s4v;
typedef __attribute__((ext_vector_type(4))) float f4v;
typedef __attribute__((ext_vector_type(16))) float f16v;

__device__ __forceinline__ float bf2f(unsigned short h){
  union{unsigned u; float f;} v; v.u = ((unsigned)h)<<16; return v.f;
}
__device__ __forceinline__ unsigned short f2bf(float f){
  union{float f; unsigned u;} v; v.f = f;
  unsigned r = v.u + 0x7fffu + ((v.u>>16)&1u);   // RNE
  return (unsigned short)(r>>16);
}
__device__ __forceinline__ unsigned cvtpk_bf16(float lo, float hi_){
  unsigned r;
  asm("v_cvt_pk_bf16_f32 %0, %1, %2" : "=v"(r) : "v"(lo), "v"(hi_));
  return r;
}
// 16B-chunk XOR swizzle (rows of 64 bf16) — used by k_proj/k_final LDS tiles
__device__ __forceinline__ s8v lds_rd8(const unsigned short* b, int row, int ck){
  return *(const s8v*)&b[(row<<6) + (((ck)^(row&7))<<3)];
}
__device__ __forceinline__ void lds_wr8(unsigned short* b, int row, int ck, s8v v){
  *(s8v*)&b[(row<<6) + (((ck)^(row&7))<<3)] = v;
}

// ---- convert 5 weight matrices fp32 -> bf16 into ws ----
__global__ __launch_bounds__(256) void k_wcvt(const float* __restrict__ w0,
    const float* __restrict__ w1, const float* __restrict__ w2,
    const float* __restrict__ w3, const float* __restrict__ w4,
    unsigned short* __restrict__ dst){
  int i = blockIdx.x*256 + threadIdx.x;
  int z = blockIdx.y;
  const float* s = (z==0)?w0:(z==1)?w1:(z==2)?w2:(z==3)?w3:w4;
  dst[z*(E_DIM*C_IN) + i] = f2bf(s[i]);
}

// ---- x (C,S) fp32 -> XaT (S,C) bf16 [relu(bn1)] and XrT (S,C) bf16 [raw] ----
__global__ __launch_bounds__(256) void k_prep(const float* __restrict__ x,
    const float* __restrict__ bw, const float* __restrict__ bb,
    const float* __restrict__ bm, const float* __restrict__ bvar,
    unsigned short* __restrict__ XaT, unsigned short* __restrict__ XrT){
  __shared__ float tile[32][33];
  int tid = threadIdx.x;
  int tx = tid & 31, ty = tid >> 5;
  int s0 = blockIdx.x*32, c0 = blockIdx.y*32;
  #pragma unroll
  for(int p=0;p<4;p++){
    int c = c0 + ty + p*8;
    tile[ty+p*8][tx] = x[c*S_DIM + s0 + tx];
  }
  __syncthreads();
  int cc = c0 + tx;
  float inv  = bw[cc] * rsqrtf(bvar[cc] + EPSV);
  float beta = bb[cc] - bm[cc]*inv;
  #pragma unroll
  for(int p=0;p<4;p++){
    int s = s0 + ty + p*8;
    float v = tile[tx][ty+p*8];
    float a = v*inv + beta; a = a>0.f?a:0.f;
    XaT[s*C_IN + cc] = f2bf(a);
    XrT[s*C_IN + cc] = f2bf(v);
  }
}

// ---- uniform projection GEMM ----
// z=0 Q ->(S,E); z=1 K -> KF fragment-ordered; z=2 V -> VF fragment-ordered;
// z=3 conv(+cbn+relu) ->(S,E)
__global__ __launch_bounds__(256) void k_proj(
    const unsigned short* __restrict__ XaT, const unsigned short* __restrict__ XrT,
    const unsigned short* __restrict__ Wb,
    const float* __restrict__ bq, const float* __restrict__ bk,
    const float* __restrict__ bvb, const float* __restrict__ bc,
    const float* __restrict__ cw, const float* __restrict__ cbb,
    const float* __restrict__ cm, const float* __restrict__ cvv,
    unsigned short* __restrict__ QT, unsigned short* __restrict__ KF,
    unsigned short* __restrict__ VF, unsigned short* __restrict__ CT){
  int z = blockIdx.z;
  const unsigned short* Xin = (z==3) ? XrT : XaT;
  const unsigned short* W   = Wb + z*(E_DIM*C_IN);
  const float* bias = (z==0)?bq:(z==1)?bk:(z==2)?bvb:bc;

  __shared__ unsigned short Als[128*64];
  __shared__ unsigned short Bls[64*64];
  int tid = threadIdx.x;
  int w = tid>>6, l = tid&63, g = l>>4, c16 = l&15;
  int wr = w>>1, wc = w&1;
  int s0 = blockIdx.x*128, e0 = blockIdx.y*64;

  f4v acc[4][2];
  #pragma unroll
  for(int m=0;m<4;m++)
    #pragma unroll
    for(int n=0;n<2;n++) acc[m][n] = (f4v){0.f,0.f,0.f,0.f};

  for(int kk=0;kk<4;kk++){
    __syncthreads();
    #pragma unroll
    for(int p=0;p<4;p++){
      int ck = p*256 + tid, row = ck>>3, ch = ck&7;
      s8v v = *(const s8v*)&Xin[(s0+row)*C_IN + kk*64 + ch*8];
      lds_wr8(Als, row, ch, v);
    }
    #pragma unroll
    for(int p=0;p<2;p++){
      int ck = p*256 + tid, row = ck>>3, ch = ck&7;
      s8v v = *(const s8v*)&W[(e0+row)*C_IN + kk*64 + ch*8];
      lds_wr8(Bls, row, ch, v);
    }
    __syncthreads();
    #pragma unroll
    for(int kb=0;kb<2;kb++){
      s8v bfr[2];
      #pragma unroll
      for(int n=0;n<2;n++) bfr[n] = lds_rd8(Bls, wc*32 + n*16 + c16, g + kb*4);
      #pragma unroll
      for(int m=0;m<4;m++){
        s8v af = lds_rd8(Als, wr*64 + m*16 + c16, g + kb*4);
        #pragma unroll
        for(int n=0;n<2;n++)
          acc[m][n] = __builtin_amdgcn_mfma_f32_16x16x32_bf16(af, bfr[n], acc[m][n], 0,0,0);
      }
    }
  }
  #pragma unroll
  for(int n=0;n<2;n++){
    int e = e0 + wc*32 + n*16 + c16;
    float bsv = bias[e];
    float cinv = 0.f, cbeta = 0.f;
    if(z==3){ cinv = cw[e]*rsqrtf(cvv[e]+EPSV); cbeta = cbb[e] - cm[e]*cinv; }
    #pragma unroll
    for(int m=0;m<4;m++){
      int sb = s0 + wr*64 + m*16 + g*4;
      #pragma unroll
      for(int i=0;i<4;i++){
        float vv = acc[m][n][i] + bsv;
        int key = sb+i;
        if(z==1){
          // K fragment-ordered: lane holds K[key=t*32+l31][d=ks*16+hi*8+j]
          int hh=e>>6, d=e&63, ks=d>>4, hi8=(d>>3)&1, j=d&7;
          int t=key>>5;
          KF[((((hh*128+t)*4+ks)*64) + hi8*32 + (key&31))*8 + j] = f2bf(vv);
        } else if(z==2){
          // V fragment-ordered: B-operand slots (validated R7/R8 mapping)
          int hh=e>>6, d=e&63, dt=d>>5, col=d&31;
          int t=key>>5, kq=key&31, half=kq>>4, rem=kq&15;
          int hi8=(rem>>2)&1, mm=(rem&3)+4*((rem>>3)&1);
          VF[(((((hh*128+t)*2+dt)*2+half)*64) + hi8*32 + col)*8 + mm] = f2bf(vv);
        } else {
          if(z==3){ vv = vv*cinv + cbeta; vv = vv>0.f?vv:0.f; }
          unsigned short* dst = (z==0)?QT:CT;
          dst[key*E_DIM + e] = f2bf(vv);
        }
      }
    }
  }
}

// ---- flash attention (fixed-max softmax) + fuse -> fusedT (S,E) bf16 ----
// Barrier-free register streaming (R8 structure) + software pipelining:
// K double-buffered in registers (kA/kB, 2-iter unrolled body, static indices),
// V loaded early each iter. 8 waves/block = 64 q x ksplit 8; grid 512 (2/CU).
// No LDS / no barriers in the loop. End: additive merge of 8 partials.
__global__ __launch_bounds__(512,4) void k_attn(
    const unsigned short* __restrict__ QT, const unsigned short* __restrict__ KF,
    const unsigned short* __restrict__ VF, const unsigned short* __restrict__ CT,
    const float* __restrict__ gamma, const float* __restrict__ temp,
    unsigned short* __restrict__ fusedT){
  __shared__ float slab[7*64*33];      // 59KB merge slab (stride 33: conflict-free)
  __shared__ float l_buf[32];
  int tid = threadIdx.x;
  int w = tid>>6, l = tid&63, l31 = l&31, hi = l>>5;
  int bx = blockIdx.x;
  int h = bx&7;                        // head-per-XCD
  int q0b = (bx>>3)*64;
  float scl = 1.4426950408889634f / temp[0];   // log2(e)/T -> exp2 path

  // Q B-fragments (pre-scaled): qf[qg][ks]
  s8v qf[2][4];
  #pragma unroll
  for(int qg=0;qg<2;qg++){
    int q = q0b + qg*32 + l31;
    #pragma unroll
    for(int ks=0;ks<4;ks++){
      s8v r = *(const s8v*)&QT[q*E_DIM + h*HD + ks*16 + hi*8];
      #pragma unroll
      for(int j=0;j<8;j++) qf[qg][ks][j] = (short)f2bf(bf2f((unsigned short)r[j])*scl);
    }
  }

  f16v oacc[2][2];   // [qg][dt]: O[q=row(r,hi)][d=dt*32+l31]
  #pragma unroll
  for(int qg=0;qg<2;qg++)
    #pragma unroll
    for(int dt=0;dt<2;dt++)
      #pragma unroll
      for(int r=0;r<16;r++) oacc[qg][dt][r]=0.f;
  float lrun[2] = {0.f, 0.f};

  // wave's 16 tiles start at tile w*16; tile stride = 2048 elems for both KF,VF
  const unsigned short* KFp = KF + ((h*128 + w*16)*4*64 + l)*8;
  const unsigned short* VFp = VF + ((h*128 + w*16)*4*64 + l)*8;

  s8v kA[4], kB[4], vf[4];
  #pragma unroll
  for(int i=0;i<4;i++) kA[i] = *(const s8v*)&KFp[i*512];

  #define ATTN_TILE(KREG) { \
    _Pragma("unroll") \
    for(int qg=0;qg<2;qg++){ \
      f16v d; \
      _Pragma("unroll") \
      for(int r=0;r<16;r++) d[r]=0.f; \
      __builtin_amdgcn_s_setprio(1); \
      d = __builtin_amdgcn_mfma_f32_32x32x16_bf16(KREG[0], qf[qg][0], d, 0,0,0); \
      d = __builtin_amdgcn_mfma_f32_32x32x16_bf16(KREG[1], qf[qg][1], d, 0,0,0); \
      d = __builtin_amdgcn_mfma_f32_32x32x16_bf16(KREG[2], qf[qg][2], d, 0,0,0); \
      d = __builtin_amdgcn_mfma_f32_32x32x16_bf16(KREG[3], qf[qg][3], d, 0,0,0); \
      __builtin_amdgcn_s_setprio(0); \
      float e_[16], ls = 0.f; \
      _Pragma("unroll") \
      for(int r=0;r<16;r++){ e_[r] = __builtin_amdgcn_exp2f(d[r]); ls += e_[r]; } \
      lrun[qg] += ls; \
      union{ s8v v; unsigned u[4]; } pa0, pa1; \
      _Pragma("unroll") \
      for(int j=0;j<4;j++){ \
        pa0.u[j] = cvtpk_bf16(e_[2*j],   e_[2*j+1]); \
        pa1.u[j] = cvtpk_bf16(e_[8+2*j], e_[8+2*j+1]); \
      } \
      __builtin_amdgcn_s_setprio(1); \
      oacc[qg][0] = __builtin_amdgcn_mfma_f32_32x32x16_bf16(pa0.v, vf[0], oacc[qg][0], 0,0,0); \
      oacc[qg][0] = __builtin_amdgcn_mfma_f32_32x32x16_bf16(pa1.v, vf[1], oacc[qg][0], 0,0,0); \
      oacc[qg][1] = __builtin_amdgcn_mfma_f32_32x32x16_bf16(pa0.v, vf[2], oacc[qg][1], 0,0,0); \
      oacc[qg][1] = __builtin_amdgcn_mfma_f32_32x32x16_bf16(pa1.v, vf[3], oacc[qg][1], 0,0,0); \
      __builtin_amdgcn_s_setprio(0); \
    } }

  #pragma unroll 1
  for(int tt=0;tt<8;tt++){
    { // even tile t=2*tt: compute with kA, prefetch kB = K(t+1)
      const int t = 2*tt;
      #pragma unroll
      for(int i=0;i<4;i++) vf[i] = *(const s8v*)&VFp[(t*4+i)*512];
      #pragma unroll
      for(int i=0;i<4;i++) kB[i] = *(const s8v*)&KFp[((t+1)*4+i)*512];
      ATTN_TILE(kA);
    }
    { // odd tile t=2*tt+1: compute with kB, prefetch kA = K(t+2) (clamped)
      const int t = 2*tt+1;
      #pragma unroll
      for(int i=0;i<4;i++) vf[i] = *(const s8v*)&VFp[(t*4+i)*512];
      const int tn = (tt<7)? (t+1) : t;
      #pragma unroll
      for(int i=0;i<4;i++) kA[i] = *(const s8v*)&KFp[(tn*4+i)*512];
      ATTN_TILE(kB);
    }
  }
  #undef ATTN_TILE

  #pragma unroll
  for(int qg=0;qg<2;qg++) lrun[qg] += __shfl_xor(lrun[qg], 32);

  // ---- merge 8 ksplit partials (additive; shared fixed max) ----
  float ga = gamma[0];
  #pragma unroll
  for(int qg=0;qg<2;qg++){
    __syncthreads();
    if(w!=0){
      float* dst = slab + ((w-1)*64 + l)*33;
      #pragma unroll
      for(int r=0;r<16;r++){ dst[r] = oacc[qg][0][r]; dst[16+r] = oacc[qg][1][r]; }
      dst[32] = lrun[qg];
    }
    __syncthreads();
    if(w==0){
      float lt = lrun[qg];
      #pragma unroll
      for(int s=0;s<7;s++){
        const float* src = slab + (s*64 + l)*33;
        #pragma unroll
        for(int r=0;r<16;r++){ oacc[qg][0][r] += src[r]; oacc[qg][1][r] += src[16+r]; }
        lt += src[32];
      }
      if(hi==0) l_buf[l31] = lt;
      #pragma unroll
      for(int dt=0;dt<2;dt++){
        int e = h*HD + dt*32 + l31;
        #pragma unroll
        for(int g4=0;g4<4;g4++){
          float4 lv = *(float4*)&l_buf[g4*8 + hi*4];
          float la[4] = {lv.x, lv.y, lv.z, lv.w};
          #pragma unroll
          for(int j=0;j<4;j++){
            int r = g4*4 + j;
            int qrow = q0b + qg*32 + j + g4*8 + hi*4;
            float o = oacc[qg][dt][r]*(ga/la[j]) + bf2f(CT[qrow*E_DIM + e]);
            fusedT[qrow*E_DIM + e] = f2bf(o);
          }
        }
      }
    }
  }
}

// ---- final: out(c,s) = gelu(rbn(rs_w . fused + rs_b)) fp32, 64x64 tiles ----
__global__ __launch_bounds__(256) void k_final(
    const unsigned short* __restrict__ Wrs,
    const unsigned short* __restrict__ fusedT,
    const float* __restrict__ rsb,
    const float* __restrict__ rw, const float* __restrict__ rbb,
    const float* __restrict__ rm, const float* __restrict__ rv,
    float* __restrict__ out){
  __shared__ unsigned short Als[64*64];
  __shared__ unsigned short Bls[64*64];
  int tid = threadIdx.x;
  int w = tid>>6, l = tid&63, g = l>>4, c16 = l&15;
  int wr2 = w>>1, wc2 = w&1;
  int sB0 = blockIdx.x*64, c0 = blockIdx.y*64;
  f4v acc[2][2];
  #pragma unroll
  for(int m=0;m<2;m++)
    #pragma unroll
    for(int n=0;n<2;n++) acc[m][n]=(f4v){0.f,0.f,0.f,0.f};
  for(int kk=0;kk<8;kk++){
    __syncthreads();
    #pragma unroll
    for(int p=0;p<2;p++){
      int ck = p*256+tid, row=ck>>3, ch=ck&7;
      s8v v = *(const s8v*)&Wrs[(c0+row)*E_DIM + kk*64 + ch*8];
      lds_wr8(Als, row, ch, v);
    }
    #pragma unroll
    for(int p=0;p<2;p++){
      int ck = p*256+tid, row=ck>>3, ch=ck&7;
      s8v v = *(const s8v*)&fusedT[(sB0+row)*E_DIM + kk*64 + ch*8];
      lds_wr8(Bls, row, ch, v);
    }
    __syncthreads();
    #pragma unroll
    for(int kb=0;kb<2;kb++){
      s8v af[2]; s8v bfr[2];
      #pragma unroll
      for(int m=0;m<2;m++) af[m] = lds_rd8(Als, wr2*32 + m*16 + c16, g + kb*4);
      #pragma unroll
      for(int n=0;n<2;n++) bfr[n] = lds_rd8(Bls, wc2*32 + n*16 + c16, g + kb*4);
      #pragma unroll
      for(int m=0;m<2;m++)
        #pragma unroll
        for(int n=0;n<2;n++)
          acc[m][n] = __builtin_amdgcn_mfma_f32_16x16x32_bf16(af[m], bfr[n], acc[m][n],0,0,0);
    }
  }
  #pragma unroll
  for(int m=0;m<2;m++){
    #pragma unroll
    for(int i=0;i<4;i++){
      int c = c0 + wr2*32 + m*16 + g*4 + i;
      float bias = rsb[c];
      float rinv = rw[c]*rsqrtf(rv[c]+EPSV);
      float rbeta = rbb[c] - rm[c]*rinv;
      #pragma unroll
      for(int n=0;n<2;n++){
        int s = sB0 + wc2*32 + n*16 + c16;
        float vv = acc[m][n][i] + bias;
        vv = vv*rinv + rbeta;
        out[c*S_DIM + s] = 0.5f*vv*(1.0f + erff(vv*0.70710678118f));
      }
    }
  }
}

extern "C" void kernel_launch(void* const* d_in, const int* in_sizes, int n_in,
                              void* d_out, int out_size, void* d_ws, size_t ws_size,
                              hipStream_t stream){
  const float* x     = (const float*)d_in[0];
  const float* bn1w  = (const float*)d_in[1];
  const float* bn1b  = (const float*)d_in[2];
  const float* bn1m  = (const float*)d_in[3];
  const float* bn1v  = (const float*)d_in[4];
  const float* Wq    = (const float*)d_in[5];
  const float* bq    = (const float*)d_in[6];
  const float* Wk    = (const float*)d_in[7];
  const float* bk    = (const float*)d_in[8];
  const float* Wv    = (const float*)d_in[9];
  const float* bv    = (const float*)d_in[10];
  const float* gamma = (const float*)d_in[11];
  const float* temp  = (const float*)d_in[12];
  const float* convw = (const float*)d_in[13];
  const float* convb = (const float*)d_in[14];
  const float* cbnw  = (const float*)d_in[15];
  const float* cbnb  = (const float*)d_in[16];
  const float* cbnm  = (const float*)d_in[17];
  const float* cbnv  = (const float*)d_in[18];
  const float* rsw   = (const float*)d_in[19];
  const float* rsbp  = (const float*)d_in[20];
  const float* rbnw  = (const float*)d_in[21];
  const float* rbnb  = (const float*)d_in[22];
  const float* rbnm  = (const float*)d_in[23];
  const float* rbnv  = (const float*)d_in[24];
  float* out = (float*)d_out;

  unsigned short* ws  = (unsigned short*)d_ws;
  unsigned short* XaT = ws;                          // (S,C) bf16
  unsigned short* XrT = XaT + S_DIM*C_IN;            // (S,C) bf16
  unsigned short* Wb  = XrT + S_DIM*C_IN;            // q,k,v,conv weights bf16
  unsigned short* Wrs = Wb + 4*E_DIM*C_IN;           // rs weight bf16 (256x512)
  unsigned short* QT  = Wrs + C_IN*E_DIM;            // (S,E)
  unsigned short* KF  = QT + S_DIM*E_DIM;            // fragment-ordered K
  unsigned short* VF  = KF + S_DIM*E_DIM;            // fragment-ordered V
  unsigned short* CT  = VF + S_DIM*E_DIM;            // (S,E) conv path
  unsigned short* fusedT = CT + S_DIM*E_DIM;         // (S,E)

  k_wcvt<<<dim3(512,5),256,0,stream>>>(Wq, Wk, Wv, convw, rsw, Wb);
  k_prep<<<dim3(128,8),256,0,stream>>>(x, bn1w, bn1b, bn1m, bn1v, XaT, XrT);
  k_proj<<<dim3(32,8,4),256,0,stream>>>(XaT, XrT, Wb, bq, bk, bv, convb,
                                        cbnw, cbnb, cbnm, cbnv, QT, KF, VF, CT);
  k_attn<<<dim3(512),512,0,stream>>>(QT, KF, VF, CT, gamma, temp, fusedT);
  k_final<<<dim3(64,4),256,0,stream>>>(Wrs, fusedT, rsbp, rbnw, rbnb, rbnm, rbnv, out);
}

// Round 12
// 84.623 us; speedup vs baseline: 4.6567x; 4.6567x over previous
//
#include <hip/hip_runtime.h>

#define S_DIM 4096
#define C_IN  256
#define E_DIM 512
#define HD    64
#define EPSV  1e-5f

typedef __attribute__((ext_vector_type(8))) short s8v;
typedef __attribute__((ext_vector_type(4))) short s4v;
typedef __attribute__((ext_vector_type(4))) float f4v;
typedef __attribute__((ext_vector_type(16))) float f16v;

__device__ __forceinline__ float bf2f(unsigned short h){
  union{unsigned u; float f;} v; v.u = ((unsigned)h)<<16; return v.f;
}
__device__ __forceinline__ unsigned short f2bf(float f){
  union{float f; unsigned u;} v; v.f = f;
  unsigned r = v.u + 0x7fffu + ((v.u>>16)&1u);   // RNE
  return (unsigned short)(r>>16);
}
__device__ __forceinline__ unsigned cvtpk_bf16(float lo, float hi_){
  unsigned r;
  asm("v_cvt_pk_bf16_f32 %0, %1, %2" : "=v"(r) : "v"(lo), "v"(hi_));
  return r;
}
// 16B-chunk XOR swizzle read (rows of 64 bf16) — content pre-swizzled in global
__device__ __forceinline__ s8v lds_rd8(const unsigned short* b, int row, int ck){
  return *(const s8v*)&b[(row<<6) + (((ck)^(row&7))<<3)];
}
__device__ __forceinline__ void lds_wr8(unsigned short* b, int row, int ck, s8v v){
  *(s8v*)&b[(row<<6) + (((ck)^(row&7))<<3)] = v;
}
// 8B-granule XOR swizzle read for V tiles
__device__ __forceinline__ s4v lds_rd4q(const unsigned short* b, int row, int q4){
  return *(const s4v*)&b[(row<<6) + (((q4)^(row&15))<<2)];
}
// async global->LDS, 16B per lane, LDS dest wave-uniform base
__device__ __forceinline__ void gl_lds16(const unsigned short* g, unsigned short* l){
  __builtin_amdgcn_global_load_lds(
      (const __attribute__((address_space(1))) unsigned int*)g,
      (__attribute__((address_space(3))) unsigned int*)l, 16, 0, 0);
}

// ---- fused preprocessing: weight cvt (blocks 0..2559) + x prep (2560..3583) ----
__global__ __launch_bounds__(256) void k_pre(const float* __restrict__ w0,
    const float* __restrict__ w1, const float* __restrict__ w2,
    const float* __restrict__ w3, const float* __restrict__ w4,
    unsigned short* __restrict__ dst,
    const float* __restrict__ x,
    const float* __restrict__ bw, const float* __restrict__ bb,
    const float* __restrict__ bm, const float* __restrict__ bvar,
    unsigned short* __restrict__ XaT, unsigned short* __restrict__ XrT){
  int fb = blockIdx.x;
  int tid = threadIdx.x;
  if(fb < 2560){
    int z = fb >> 9, i = (fb & 511)*256 + tid;
    const float* s = (z==0)?w0:(z==1)?w1:(z==2)?w2:(z==3)?w3:w4;
    dst[z*(E_DIM*C_IN) + i] = f2bf(s[i]);
    return;
  }
  int b = fb - 2560;
  __shared__ float tile[32][33];
  int tx = tid & 31, ty = tid >> 5;
  int s0 = (b & 127)*32, c0 = (b >> 7)*32;
  #pragma unroll
  for(int p=0;p<4;p++){
    int c = c0 + ty + p*8;
    tile[ty+p*8][tx] = x[c*S_DIM + s0 + tx];
  }
  __syncthreads();
  int cc = c0 + tx;
  float inv  = bw[cc] * rsqrtf(bvar[cc] + EPSV);
  float beta = bb[cc] - bm[cc]*inv;
  #pragma unroll
  for(int p=0;p<4;p++){
    int s = s0 + ty + p*8;
    float v = tile[tx][ty+p*8];
    float a = v*inv + beta; a = a>0.f?a:0.f;
    XaT[s*C_IN + cc] = f2bf(a);
    XrT[s*C_IN + cc] = f2bf(v);
  }
}

// ---- uniform projection GEMM ----
// Grid (8 e-blocks/heads, 32 s-blocks, 4 z): flat%8 = e-block = head -> the
// XCD writing head h's K/V/Q slice is the XCD that k_attn reads it from.
// z=0 Q ->(S,E), z=1 K ->(S,E) chunk-swizzled, z=2 V ->(E,S) granule-swizzled,
// z=3 conv(+cbn+relu) ->(S,E)
__global__ __launch_bounds__(256) void k_proj(
    const unsigned short* __restrict__ XaT, const unsigned short* __restrict__ XrT,
    const unsigned short* __restrict__ Wb,
    const float* __restrict__ bq, const float* __restrict__ bk,
    const float* __restrict__ bvb, const float* __restrict__ bc,
    const float* __restrict__ cw, const float* __restrict__ cbb,
    const float* __restrict__ cm, const float* __restrict__ cvv,
    unsigned short* __restrict__ QT, unsigned short* __restrict__ KT,
    unsigned short* __restrict__ Vx, unsigned short* __restrict__ CT){
  int z = blockIdx.z;
  const unsigned short* Xin = (z==3) ? XrT : XaT;
  const unsigned short* W   = Wb + z*(E_DIM*C_IN);
  const float* bias = (z==0)?bq:(z==1)?bk:(z==2)?bvb:bc;

  __shared__ unsigned short Als[128*64];
  __shared__ unsigned short Bls[64*64];
  int tid = threadIdx.x;
  int w = tid>>6, l = tid&63, g = l>>4, c16 = l&15;
  int wr = w>>1, wc = w&1;
  int s0 = blockIdx.y*128, e0 = blockIdx.x*64;

  f4v acc[4][2];
  #pragma unroll
  for(int m=0;m<4;m++)
    #pragma unroll
    for(int n=0;n<2;n++) acc[m][n] = (f4v){0.f,0.f,0.f,0.f};

  for(int kk=0;kk<4;kk++){
    __syncthreads();
    #pragma unroll
    for(int p=0;p<4;p++){
      int ck = p*256 + tid, row = ck>>3, ch = ck&7;
      s8v v = *(const s8v*)&Xin[(s0+row)*C_IN + kk*64 + ch*8];
      lds_wr8(Als, row, ch, v);
    }
    #pragma unroll
    for(int p=0;p<2;p++){
      int ck = p*256 + tid, row = ck>>3, ch = ck&7;
      s8v v = *(const s8v*)&W[(e0+row)*C_IN + kk*64 + ch*8];
      lds_wr8(Bls, row, ch, v);
    }
    __syncthreads();
    #pragma unroll
    for(int kb=0;kb<2;kb++){
      s8v bfr[2];
      #pragma unroll
      for(int n=0;n<2;n++) bfr[n] = lds_rd8(Bls, wc*32 + n*16 + c16, g + kb*4);
      #pragma unroll
      for(int m=0;m<4;m++){
        s8v af = lds_rd8(Als, wr*64 + m*16 + c16, g + kb*4);
        #pragma unroll
        for(int n=0;n<2;n++)
          acc[m][n] = __builtin_amdgcn_mfma_f32_16x16x32_bf16(af, bfr[n], acc[m][n], 0,0,0);
      }
    }
  }
  #pragma unroll
  for(int n=0;n<2;n++){
    int e = e0 + wc*32 + n*16 + c16;
    float bsv = bias[e];
    float cinv = 0.f, cbeta = 0.f;
    if(z==3){ cinv = cw[e]*rsqrtf(cvv[e]+EPSV); cbeta = cbb[e] - cm[e]*cinv; }
    #pragma unroll
    for(int m=0;m<4;m++){
      int sb = s0 + wr*64 + m*16 + g*4;
      if(z==2){
        s4v pk;
        #pragma unroll
        for(int i=0;i<4;i++) pk[i] = (short)f2bf(acc[m][n][i] + bsv);
        // bake 8B-granule XOR swizzle into the key position (within 64-key tile)
        int sb2 = (sb & ~63) | ((((sb>>2)&15) ^ (e&15))<<2);
        *(s4v*)&Vx[e*S_DIM + sb2] = pk;
      } else {
        unsigned short* dst = (z==0)?QT:(z==1)?KT:CT;
        #pragma unroll
        for(int i=0;i<4;i++){
          float vv = acc[m][n][i] + bsv;
          if(z==3){ vv = vv*cinv + cbeta; vv = vv>0.f?vv:0.f; }
          int key = sb+i;
          int ee = e;
          if(z==1) ee = (e & ~56) | ((((e>>3)&7) ^ (key&7))<<3); // 16B-chunk swizzle
          dst[key*E_DIM + ee] = f2bf(vv);
        }
      }
    }
  }
}

// ---- flash attention (fixed-max softmax) + fuse -> fusedT (S,E) bf16 ----
// R10 structure (verified): 512 thr, 8 waves = (qh x2, kh x4), 128 q/block,
// grid 256 (1/CU), dbuf 2x64KB, vmcnt(0)+syncthreads then STAGE(t+1).
// K/V now written by the SAME XCD that reads them (k_proj affinity).
__global__ __launch_bounds__(512,2) void k_attn(
    const unsigned short* __restrict__ QT, const unsigned short* __restrict__ KT,
    const unsigned short* __restrict__ Vx, const unsigned short* __restrict__ CT,
    const float* __restrict__ gamma, const float* __restrict__ temp,
    unsigned short* __restrict__ fusedT){
  __shared__ unsigned short SM[65536];   // 2 bufs x 8 tiles x 8KB = 128KB
  int tid = threadIdx.x;
  int w = tid>>6, l = tid&63, l31 = l&31, hi = l>>5;
  int qh = w>>2, kh = w&3;
  int bx = blockIdx.x;
  int h = bx&7;                           // head-per-XCD
  int q0b = (bx>>3)*128;
  float scl = 1.4426950408889634f / temp[0];   // log2(e)/T -> exp2 path

  // ---- staging: 8 DMA instrs/thread; flat 16B-granule = (w*8+j)*64 + lane ----
  #define STAGE(BUF, T) { \
    _Pragma("unroll") \
    for(int j=0;j<8;j++){ \
      int flat = (w*8+j)*64 + l; \
      int tile = flat>>9, gg = flat&511, row = gg>>3, ch = gg&7; \
      int khp = tile&3; \
      int sK = khp*1024 + (T)*64; \
      const unsigned short* src = (tile<4) \
        ? &KT[(sK+row)*E_DIM + h*HD + ch*8] \
        : &Vx[(h*HD+row)*S_DIM + sK + ch*8]; \
      gl_lds16(src, SM + (BUF)*32768 + (w*8+j)*512); \
    } }

  STAGE(0, 0);

  // Q B-fragments (pre-scaled): qf[qg][ks]
  s8v qf[2][4];
  #pragma unroll
  for(int qg=0;qg<2;qg++){
    int q = q0b + qh*64 + qg*32 + l31;
    #pragma unroll
    for(int ks=0;ks<4;ks++){
      s8v r = *(const s8v*)&QT[q*E_DIM + h*HD + ks*16 + hi*8];
      #pragma unroll
      for(int j=0;j<8;j++) qf[qg][ks][j] = (short)f2bf(bf2f((unsigned short)r[j])*scl);
    }
  }

  f16v oacc[2][2];   // [qg][dt]
  #pragma unroll
  for(int qg=0;qg<2;qg++)
    #pragma unroll
    for(int dt=0;dt<2;dt++)
      #pragma unroll
      for(int r=0;r<16;r++) oacc[qg][dt][r]=0.f;
  float lrun[2] = {0.f, 0.f};

  int buf = 0;
  #pragma unroll 1
  for(int t=0;t<16;t++){
    asm volatile("s_waitcnt vmcnt(0)" ::: "memory");
    __syncthreads();
    if(t<15) STAGE(buf^1, t+1);
    const unsigned short* Kb = SM + buf*32768 + kh*4096;
    const unsigned short* Vb = SM + buf*32768 + (4+kh)*4096;

    #pragma unroll
    for(int sub=0;sub<2;sub++){
      int kr = sub*32 + l31;
      s8v kf[4];
      #pragma unroll
      for(int ks=0;ks<4;ks++) kf[ks] = lds_rd8(Kb, kr, ks*2 + hi);

      union{ s8v v; unsigned u[4]; } pa[2][2];   // [qg][half]
      #pragma unroll
      for(int qg=0;qg<2;qg++){
        f16v d;
        #pragma unroll
        for(int r=0;r<16;r++) d[r]=0.f;
        __builtin_amdgcn_s_setprio(1);
        #pragma unroll
        for(int ks=0;ks<4;ks++)
          d = __builtin_amdgcn_mfma_f32_32x32x16_bf16(kf[ks], qf[qg][ks], d, 0,0,0);
        __builtin_amdgcn_s_setprio(0);
        float e_[16], ls = 0.f;
        #pragma unroll
        for(int r=0;r<16;r++){ e_[r] = __builtin_amdgcn_exp2f(d[r]); ls += e_[r]; }
        lrun[qg] += ls;
        #pragma unroll
        for(int j=0;j<4;j++){
          pa[qg][0].u[j] = cvtpk_bf16(e_[2*j],   e_[2*j+1]);
          pa[qg][1].u[j] = cvtpk_bf16(e_[8+2*j], e_[8+2*j+1]);
        }
      }
      __builtin_amdgcn_s_setprio(1);
      #pragma unroll
      for(int dt=0;dt<2;dt++){
        int vr = dt*32 + l31;
        union{ s8v v; s4v h2[2]; } vf;
        vf.h2[0] = lds_rd4q(Vb, vr, sub*8 + hi);
        vf.h2[1] = lds_rd4q(Vb, vr, sub*8 + 2 + hi);
        oacc[0][dt] = __builtin_amdgcn_mfma_f32_32x32x16_bf16(pa[0][0].v, vf.v, oacc[0][dt], 0,0,0);
        oacc[1][dt] = __builtin_amdgcn_mfma_f32_32x32x16_bf16(pa[1][0].v, vf.v, oacc[1][dt], 0,0,0);
        vf.h2[0] = lds_rd4q(Vb, vr, sub*8 + 4 + hi);
        vf.h2[1] = lds_rd4q(Vb, vr, sub*8 + 6 + hi);
        oacc[0][dt] = __builtin_amdgcn_mfma_f32_32x32x16_bf16(pa[0][1].v, vf.v, oacc[0][dt], 0,0,0);
        oacc[1][dt] = __builtin_amdgcn_mfma_f32_32x32x16_bf16(pa[1][1].v, vf.v, oacc[1][dt], 0,0,0);
      }
      __builtin_amdgcn_s_setprio(0);
    }
    buf ^= 1;
  }

  #pragma unroll
  for(int qg=0;qg<2;qg++) lrun[qg] += __shfl_xor(lrun[qg], 32);

  // ---- merge 4 kh-waves per qh group; additive (shared fixed max) ----
  float* slab = (float*)SM;          // [qh*3+(kh-1)][64 lanes][33] = 50688 B
  float* l_buf = slab + 6*64*33;     // 64 floats
  float ga = gamma[0];
  #pragma unroll
  for(int qg=0;qg<2;qg++){
    __syncthreads();
    if(kh!=0){
      float* dst = slab + ((qh*3 + (kh-1))*64 + l)*33;
      #pragma unroll
      for(int r=0;r<16;r++){ dst[r] = oacc[qg][0][r]; dst[16+r] = oacc[qg][1][r]; }
      dst[32] = lrun[qg];
    }
    __syncthreads();
    if(kh==0){
      float lt = lrun[qg];
      #pragma unroll
      for(int s=0;s<3;s++){
        const float* src = slab + ((qh*3 + s)*64 + l)*33;
        #pragma unroll
        for(int r=0;r<16;r++){ oacc[qg][0][r] += src[r]; oacc[qg][1][r] += src[16+r]; }
        lt += src[32];
      }
      if(hi==0) l_buf[qh*32 + l31] = lt;
    }
    __syncthreads();
    if(kh==0){
      #pragma unroll
      for(int g4=0;g4<4;g4++){
        float4 lv = *(float4*)&l_buf[qh*32 + g4*8 + hi*4];
        float rl[4] = {ga/lv.x, ga/lv.y, ga/lv.z, ga/lv.w};
        #pragma unroll
        for(int dt=0;dt<2;dt++){
          int e = h*HD + dt*32 + l31;
          #pragma unroll
          for(int j=0;j<4;j++){
            int r = g4*4 + j;
            int qrow = q0b + qh*64 + qg*32 + j + g4*8 + hi*4;
            float o = oacc[qg][dt][r]*rl[j] + bf2f(CT[qrow*E_DIM + e]);
            fusedT[qrow*E_DIM + e] = f2bf(o);
          }
        }
      }
    }
  }
  #undef STAGE
}

// ---- final: out(c,s) = gelu(rbn(rs_w . fused + rs_b)) fp32, 64x64 tiles ----
__global__ __launch_bounds__(256) void k_final(
    const unsigned short* __restrict__ Wrs,
    const unsigned short* __restrict__ fusedT,
    const float* __restrict__ rsb,
    const float* __restrict__ rw, const float* __restrict__ rbb,
    const float* __restrict__ rm, const float* __restrict__ rv,
    float* __restrict__ out){
  __shared__ unsigned short Als[64*64];
  __shared__ unsigned short Bls[64*64];
  int tid = threadIdx.x;
  int w = tid>>6, l = tid&63, g = l>>4, c16 = l&15;
  int wr2 = w>>1, wc2 = w&1;
  int sB0 = blockIdx.x*64, c0 = blockIdx.y*64;
  f4v acc[2][2];
  #pragma unroll
  for(int m=0;m<2;m++)
    #pragma unroll
    for(int n=0;n<2;n++) acc[m][n]=(f4v){0.f,0.f,0.f,0.f};
  for(int kk=0;kk<8;kk++){
    __syncthreads();
    #pragma unroll
    for(int p=0;p<2;p++){
      int ck = p*256+tid, row=ck>>3, ch=ck&7;
      s8v v = *(const s8v*)&Wrs[(c0+row)*E_DIM + kk*64 + ch*8];
      lds_wr8(Als, row, ch, v);
    }
    #pragma unroll
    for(int p=0;p<2;p++){
      int ck = p*256+tid, row=ck>>3, ch=ck&7;
      s8v v = *(const s8v*)&fusedT[(sB0+row)*E_DIM + kk*64 + ch*8];
      lds_wr8(Bls, row, ch, v);
    }
    __syncthreads();
    #pragma unroll
    for(int kb=0;kb<2;kb++){
      s8v af[2]; s8v bfr[2];
      #pragma unroll
      for(int m=0;m<2;m++) af[m] = lds_rd8(Als, wr2*32 + m*16 + c16, g + kb*4);
      #pragma unroll
      for(int n=0;n<2;n++) bfr[n] = lds_rd8(Bls, wc2*32 + n*16 + c16, g + kb*4);
      #pragma unroll
      for(int m=0;m<2;m++)
        #pragma unroll
        for(int n=0;n<2;n++)
          acc[m][n] = __builtin_amdgcn_mfma_f32_16x16x32_bf16(af[m], bfr[n], acc[m][n],0,0,0);
    }
  }
  #pragma unroll
  for(int m=0;m<2;m++){
    #pragma unroll
    for(int i=0;i<4;i++){
      int c = c0 + wr2*32 + m*16 + g*4 + i;
      float bias = rsb[c];
      float rinv = rw[c]*rsqrtf(rv[c]+EPSV);
      float rbeta = rbb[c] - rm[c]*rinv;
      #pragma unroll
      for(int n=0;n<2;n++){
        int s = sB0 + wc2*32 + n*16 + c16;
        float vv = acc[m][n][i] + bias;
        vv = vv*rinv + rbeta;
        out[c*S_DIM + s] = 0.5f*vv*(1.0f + erff(vv*0.70710678118f));
      }
    }
  }
}

extern "C" void kernel_launch(void* const* d_in, const int* in_sizes, int n_in,
                              void* d_out, int out_size, void* d_ws, size_t ws_size,
                              hipStream_t stream){
  const float* x     = (const float*)d_in[0];
  const float* bn1w  = (const float*)d_in[1];
  const float* bn1b  = (const float*)d_in[2];
  const float* bn1m  = (const float*)d_in[3];
  const float* bn1v  = (const float*)d_in[4];
  const float* Wq    = (const float*)d_in[5];
  const float* bq    = (const float*)d_in[6];
  const float* Wk    = (const float*)d_in[7];
  const float* bk    = (const float*)d_in[8];
  const float* Wv    = (const float*)d_in[9];
  const float* bv    = (const float*)d_in[10];
  const float* gamma = (const float*)d_in[11];
  const float* temp  = (const float*)d_in[12];
  const float* convw = (const float*)d_in[13];
  const float* convb = (const float*)d_in[14];
  const float* cbnw  = (const float*)d_in[15];
  const float* cbnb  = (const float*)d_in[16];
  const float* cbnm  = (const float*)d_in[17];
  const float* cbnv  = (const float*)d_in[18];
  const float* rsw   = (const float*)d_in[19];
  const float* rsbp  = (const float*)d_in[20];
  const float* rbnw  = (const float*)d_in[21];
  const float* rbnb  = (const float*)d_in[22];
  const float* rbnm  = (const float*)d_in[23];
  const float* rbnv  = (const float*)d_in[24];
  float* out = (float*)d_out;

  unsigned short* ws  = (unsigned short*)d_ws;
  unsigned short* XaT = ws;                          // (S,C) bf16
  unsigned short* XrT = XaT + S_DIM*C_IN;            // (S,C) bf16
  unsigned short* Wb  = XrT + S_DIM*C_IN;            // q,k,v,conv weights bf16
  unsigned short* Wrs = Wb + 4*E_DIM*C_IN;           // rs weight bf16 (256x512)
  unsigned short* QT  = Wrs + C_IN*E_DIM;            // (S,E)
  unsigned short* KT  = QT + S_DIM*E_DIM;            // (S,E) chunk-swizzled
  unsigned short* Vx  = KT + S_DIM*E_DIM;            // (E,S) granule-swizzled
  unsigned short* CT  = Vx + S_DIM*E_DIM;            // (S,E) conv path
  unsigned short* fusedT = CT + S_DIM*E_DIM;         // (S,E)

  k_pre<<<dim3(3584),256,0,stream>>>(Wq, Wk, Wv, convw, rsw, Wb,
                                     x, bn1w, bn1b, bn1m, bn1v, XaT, XrT);
  k_proj<<<dim3(8,32,4),256,0,stream>>>(XaT, XrT, Wb, bq, bk, bv, convb,
                                        cbnw, cbnb, cbnm, cbnv, QT, KT, Vx, CT);
  k_attn<<<dim3(256),512,0,stream>>>(QT, KT, Vx, CT, gamma, temp, fusedT);
  k_final<<<dim3(64,4),256,0,stream>>>(Wrs, fusedT, rsbp, rbnw, rbnb, rbnm, rbnv, out);
}

// Round 13
// 77.548 us; speedup vs baseline: 5.0816x; 1.0912x over previous
//
#include <hip/hip_runtime.h>

#define S_DIM 4096
#define C_IN  256
#define E_DIM 512
#define HD    64
#define EPSV  1e-5f

typedef __attribute__((ext_vector_type(8))) short s8v;
typedef __attribute__((ext_vector_type(4))) short s4v;
typedef __attribute__((ext_vector_type(4))) float f4v;
typedef __attribute__((ext_vector_type(16))) float f16v;

__device__ __forceinline__ float bf2f(unsigned short h){
  union{unsigned u; float f;} v; v.u = ((unsigned)h)<<16; return v.f;
}
__device__ __forceinline__ unsigned short f2bf(float f){
  union{float f; unsigned u;} v; v.f = f;
  unsigned r = v.u + 0x7fffu + ((v.u>>16)&1u);   // RNE
  return (unsigned short)(r>>16);
}
__device__ __forceinline__ unsigned cvtpk_bf16(float lo, float hi_){
  unsigned r;
  asm("v_cvt_pk_bf16_f32 %0, %1, %2" : "=v"(r) : "v"(lo), "v"(hi_));
  return r;
}
// 16B-chunk XOR swizzle read (rows of 64 bf16) — content pre-swizzled in global
__device__ __forceinline__ s8v lds_rd8(const unsigned short* b, int row, int ck){
  return *(const s8v*)&b[(row<<6) + (((ck)^(row&7))<<3)];
}
// 8B-granule XOR swizzle read for V tiles
__device__ __forceinline__ s4v lds_rd4q(const unsigned short* b, int row, int q4){
  return *(const s4v*)&b[(row<<6) + (((q4)^(row&15))<<2)];
}
// chunk-swizzle an element column index within its 64-col block by row&7
__device__ __forceinline__ int swz64(int col, int row){
  return (col & ~56) | ((((col>>3)&7) ^ (row&7))<<3);
}
// async global->LDS, 16B per lane, LDS dest wave-uniform base
__device__ __forceinline__ void gl_lds16(const unsigned short* g, unsigned short* l){
  __builtin_amdgcn_global_load_lds(
      (const __attribute__((address_space(1))) unsigned int*)g,
      (__attribute__((address_space(3))) unsigned int*)l, 16, 0, 0);
}

// ---- fused preprocessing: weight cvt (blocks 0..2559) + x prep (2560..3583) ----
// All outputs PRE-SWIZZLED (16B-chunk XOR per tile-row) for DMA staging.
__global__ __launch_bounds__(256) void k_pre(const float* __restrict__ w0,
    const float* __restrict__ w1, const float* __restrict__ w2,
    const float* __restrict__ w3, const float* __restrict__ w4,
    unsigned short* __restrict__ dst,
    const float* __restrict__ x,
    const float* __restrict__ bw, const float* __restrict__ bb,
    const float* __restrict__ bm, const float* __restrict__ bvar,
    unsigned short* __restrict__ XaT, unsigned short* __restrict__ XrT){
  int fb = blockIdx.x;
  int tid = threadIdx.x;
  if(fb < 2560){
    int z = fb >> 9, i = (fb & 511)*256 + tid;
    const float* s = (z==0)?w0:(z==1)?w1:(z==2)?w2:(z==3)?w3:w4;
    float v = s[i];
    int idx;
    if(z < 4){                 // (E,C): row=e, swizzle c within 64-blocks
      int e = i>>8, c = i&255;
      idx = z*(E_DIM*C_IN) + e*C_IN + swz64(c, e);
    } else {                   // Wrs (C,E): row=c, swizzle e within 64-blocks
      int c = i>>9, e = i&511;
      idx = 4*(E_DIM*C_IN) + c*E_DIM + swz64(e, c);
    }
    dst[idx] = f2bf(v);
    return;
  }
  int b = fb - 2560;
  __shared__ float tile[32][33];
  int tx = tid & 31, ty = tid >> 5;
  int s0 = (b & 127)*32, c0 = (b >> 7)*32;
  #pragma unroll
  for(int p=0;p<4;p++){
    int c = c0 + ty + p*8;
    tile[ty+p*8][tx] = x[c*S_DIM + s0 + tx];
  }
  __syncthreads();
  int cc = c0 + tx;
  float inv  = bw[cc] * rsqrtf(bvar[cc] + EPSV);
  float beta = bb[cc] - bm[cc]*inv;
  #pragma unroll
  for(int p=0;p<4;p++){
    int s = s0 + ty + p*8;
    float v = tile[tx][ty+p*8];
    float a = v*inv + beta; a = a>0.f?a:0.f;
    int ccp = swz64(cc, s);
    XaT[s*C_IN + ccp] = f2bf(a);
    XrT[s*C_IN + ccp] = f2bf(v);
  }
}

// ---- uniform projection GEMM (DMA-staged from pre-swizzled sources) ----
// Grid (8 e-blocks/heads, 32 s-blocks, 4 z).
// z=0 Q ->(S,E), z=1 K ->(S,E) chunk-swizzled, z=2 V ->(E,S) granule-swizzled,
// z=3 conv(+cbn+relu) ->(S,E)
__global__ __launch_bounds__(256) void k_proj(
    const unsigned short* __restrict__ XaT, const unsigned short* __restrict__ XrT,
    const unsigned short* __restrict__ Wb,
    const float* __restrict__ bq, const float* __restrict__ bk,
    const float* __restrict__ bvb, const float* __restrict__ bc,
    const float* __restrict__ cw, const float* __restrict__ cbb,
    const float* __restrict__ cm, const float* __restrict__ cvv,
    unsigned short* __restrict__ QT, unsigned short* __restrict__ KT,
    unsigned short* __restrict__ Vx, unsigned short* __restrict__ CT){
  int z = blockIdx.z;
  const unsigned short* Xin = (z==3) ? XrT : XaT;
  const unsigned short* W   = Wb + z*(E_DIM*C_IN);
  const float* bias = (z==0)?bq:(z==1)?bk:(z==2)?bvb:bc;

  __shared__ unsigned short Als[128*64];
  __shared__ unsigned short Bls[64*64];
  int tid = threadIdx.x;
  int w = tid>>6, l = tid&63, g = l>>4, c16 = l&15;
  int wr = w>>1, wc = w&1;
  int s0 = blockIdx.y*128, e0 = blockIdx.x*64;

  f4v acc[4][2];
  #pragma unroll
  for(int m=0;m<4;m++)
    #pragma unroll
    for(int n=0;n<2;n++) acc[m][n] = (f4v){0.f,0.f,0.f,0.f};

  for(int kk=0;kk<4;kk++){
    __syncthreads();                       // protect previous iter's reads
    #pragma unroll
    for(int p=0;p<4;p++){                  // A tile: 1024 chunks, 4/thread
      int flat = p*256 + tid, row = flat>>3, ch = flat&7;
      gl_lds16(&Xin[(s0+row)*C_IN + kk*64 + ch*8], Als + (p*256 + w*64)*8);
    }
    #pragma unroll
    for(int p=0;p<2;p++){                  // B tile: 512 chunks, 2/thread
      int flat = p*256 + tid, row = flat>>3, ch = flat&7;
      gl_lds16(&W[(e0+row)*C_IN + kk*64 + ch*8], Bls + (p*256 + w*64)*8);
    }
    asm volatile("s_waitcnt vmcnt(0)" ::: "memory");
    __syncthreads();
    #pragma unroll
    for(int kb=0;kb<2;kb++){
      s8v bfr[2];
      #pragma unroll
      for(int n=0;n<2;n++) bfr[n] = lds_rd8(Bls, wc*32 + n*16 + c16, g + kb*4);
      #pragma unroll
      for(int m=0;m<4;m++){
        s8v af = lds_rd8(Als, wr*64 + m*16 + c16, g + kb*4);
        #pragma unroll
        for(int n=0;n<2;n++)
          acc[m][n] = __builtin_amdgcn_mfma_f32_16x16x32_bf16(af, bfr[n], acc[m][n], 0,0,0);
      }
    }
  }
  #pragma unroll
  for(int n=0;n<2;n++){
    int e = e0 + wc*32 + n*16 + c16;
    float bsv = bias[e];
    float cinv = 0.f, cbeta = 0.f;
    if(z==3){ cinv = cw[e]*rsqrtf(cvv[e]+EPSV); cbeta = cbb[e] - cm[e]*cinv; }
    #pragma unroll
    for(int m=0;m<4;m++){
      int sb = s0 + wr*64 + m*16 + g*4;
      if(z==2){
        s4v pk;
        #pragma unroll
        for(int i=0;i<4;i++) pk[i] = (short)f2bf(acc[m][n][i] + bsv);
        // bake 8B-granule XOR swizzle into the key position (within 64-key tile)
        int sb2 = (sb & ~63) | ((((sb>>2)&15) ^ (e&15))<<2);
        *(s4v*)&Vx[e*S_DIM + sb2] = pk;
      } else {
        unsigned short* dst = (z==0)?QT:(z==1)?KT:CT;
        #pragma unroll
        for(int i=0;i<4;i++){
          float vv = acc[m][n][i] + bsv;
          if(z==3){ vv = vv*cinv + cbeta; vv = vv>0.f?vv:0.f; }
          int key = sb+i;
          int ee = e;
          if(z==1) ee = swz64(e, key);     // 16B-chunk swizzle for k_attn staging
          dst[key*E_DIM + ee] = f2bf(vv);
        }
      }
    }
  }
}

// ---- flash attention (fixed-max softmax) + fuse -> fusedT (S,E) bf16 ----
// R10 structure (verified): 512 thr, 8 waves = (qh x2, kh x4), 128 q/block,
// grid 256 (1/CU), dbuf 2x64KB, vmcnt(0)+syncthreads then STAGE(t+1).
// Epilogue now writes fusedT pre-swizzled (per q-row) for k_final DMA staging.
__global__ __launch_bounds__(512,2) void k_attn(
    const unsigned short* __restrict__ QT, const unsigned short* __restrict__ KT,
    const unsigned short* __restrict__ Vx, const unsigned short* __restrict__ CT,
    const float* __restrict__ gamma, const float* __restrict__ temp,
    unsigned short* __restrict__ fusedT){
  __shared__ unsigned short SM[65536];   // 2 bufs x 8 tiles x 8KB = 128KB
  int tid = threadIdx.x;
  int w = tid>>6, l = tid&63, l31 = l&31, hi = l>>5;
  int qh = w>>2, kh = w&3;
  int bx = blockIdx.x;
  int h = bx&7;                           // head-per-XCD
  int q0b = (bx>>3)*128;
  float scl = 1.4426950408889634f / temp[0];   // log2(e)/T -> exp2 path

  // ---- staging: 8 DMA instrs/thread; flat 16B-granule = (w*8+j)*64 + lane ----
  #define STAGE(BUF, T) { \
    _Pragma("unroll") \
    for(int j=0;j<8;j++){ \
      int flat = (w*8+j)*64 + l; \
      int tile = flat>>9, gg = flat&511, row = gg>>3, ch = gg&7; \
      int khp = tile&3; \
      int sK = khp*1024 + (T)*64; \
      const unsigned short* src = (tile<4) \
        ? &KT[(sK+row)*E_DIM + h*HD + ch*8] \
        : &Vx[(h*HD+row)*S_DIM + sK + ch*8]; \
      gl_lds16(src, SM + (BUF)*32768 + (w*8+j)*512); \
    } }

  STAGE(0, 0);

  // Q B-fragments (pre-scaled): qf[qg][ks]
  s8v qf[2][4];
  #pragma unroll
  for(int qg=0;qg<2;qg++){
    int q = q0b + qh*64 + qg*32 + l31;
    #pragma unroll
    for(int ks=0;ks<4;ks++){
      s8v r = *(const s8v*)&QT[q*E_DIM + h*HD + ks*16 + hi*8];
      #pragma unroll
      for(int j=0;j<8;j++) qf[qg][ks][j] = (short)f2bf(bf2f((unsigned short)r[j])*scl);
    }
  }

  f16v oacc[2][2];   // [qg][dt]
  #pragma unroll
  for(int qg=0;qg<2;qg++)
    #pragma unroll
    for(int dt=0;dt<2;dt++)
      #pragma unroll
      for(int r=0;r<16;r++) oacc[qg][dt][r]=0.f;
  float lrun[2] = {0.f, 0.f};

  int buf = 0;
  #pragma unroll 1
  for(int t=0;t<16;t++){
    asm volatile("s_waitcnt vmcnt(0)" ::: "memory");
    __syncthreads();
    if(t<15) STAGE(buf^1, t+1);
    const unsigned short* Kb = SM + buf*32768 + kh*4096;
    const unsigned short* Vb = SM + buf*32768 + (4+kh)*4096;

    #pragma unroll
    for(int sub=0;sub<2;sub++){
      int kr = sub*32 + l31;
      s8v kf[4];
      #pragma unroll
      for(int ks=0;ks<4;ks++) kf[ks] = lds_rd8(Kb, kr, ks*2 + hi);

      union{ s8v v; unsigned u[4]; } pa[2][2];   // [qg][half]
      #pragma unroll
      for(int qg=0;qg<2;qg++){
        f16v d;
        #pragma unroll
        for(int r=0;r<16;r++) d[r]=0.f;
        __builtin_amdgcn_s_setprio(1);
        #pragma unroll
        for(int ks=0;ks<4;ks++)
          d = __builtin_amdgcn_mfma_f32_32x32x16_bf16(kf[ks], qf[qg][ks], d, 0,0,0);
        __builtin_amdgcn_s_setprio(0);
        float e_[16], ls = 0.f;
        #pragma unroll
        for(int r=0;r<16;r++){ e_[r] = __builtin_amdgcn_exp2f(d[r]); ls += e_[r]; }
        lrun[qg] += ls;
        #pragma unroll
        for(int j=0;j<4;j++){
          pa[qg][0].u[j] = cvtpk_bf16(e_[2*j],   e_[2*j+1]);
          pa[qg][1].u[j] = cvtpk_bf16(e_[8+2*j], e_[8+2*j+1]);
        }
      }
      __builtin_amdgcn_s_setprio(1);
      #pragma unroll
      for(int dt=0;dt<2;dt++){
        int vr = dt*32 + l31;
        union{ s8v v; s4v h2[2]; } vf;
        vf.h2[0] = lds_rd4q(Vb, vr, sub*8 + hi);
        vf.h2[1] = lds_rd4q(Vb, vr, sub*8 + 2 + hi);
        oacc[0][dt] = __builtin_amdgcn_mfma_f32_32x32x16_bf16(pa[0][0].v, vf.v, oacc[0][dt], 0,0,0);
        oacc[1][dt] = __builtin_amdgcn_mfma_f32_32x32x16_bf16(pa[1][0].v, vf.v, oacc[1][dt], 0,0,0);
        vf.h2[0] = lds_rd4q(Vb, vr, sub*8 + 4 + hi);
        vf.h2[1] = lds_rd4q(Vb, vr, sub*8 + 6 + hi);
        oacc[0][dt] = __builtin_amdgcn_mfma_f32_32x32x16_bf16(pa[0][1].v, vf.v, oacc[0][dt], 0,0,0);
        oacc[1][dt] = __builtin_amdgcn_mfma_f32_32x32x16_bf16(pa[1][1].v, vf.v, oacc[1][dt], 0,0,0);
      }
      __builtin_amdgcn_s_setprio(0);
    }
    buf ^= 1;
  }

  #pragma unroll
  for(int qg=0;qg<2;qg++) lrun[qg] += __shfl_xor(lrun[qg], 32);

  // ---- merge 4 kh-waves per qh group; additive (shared fixed max) ----
  float* slab = (float*)SM;          // [qh*3+(kh-1)][64 lanes][33] = 50688 B
  float* l_buf = slab + 6*64*33;     // 64 floats
  float ga = gamma[0];
  #pragma unroll
  for(int qg=0;qg<2;qg++){
    __syncthreads();
    if(kh!=0){
      float* dst = slab + ((qh*3 + (kh-1))*64 + l)*33;
      #pragma unroll
      for(int r=0;r<16;r++){ dst[r] = oacc[qg][0][r]; dst[16+r] = oacc[qg][1][r]; }
      dst[32] = lrun[qg];
    }
    __syncthreads();
    if(kh==0){
      float lt = lrun[qg];
      #pragma unroll
      for(int s=0;s<3;s++){
        const float* src = slab + ((qh*3 + s)*64 + l)*33;
        #pragma unroll
        for(int r=0;r<16;r++){ oacc[qg][0][r] += src[r]; oacc[qg][1][r] += src[16+r]; }
        lt += src[32];
      }
      if(hi==0) l_buf[qh*32 + l31] = lt;
    }
    __syncthreads();
    if(kh==0){
      #pragma unroll
      for(int g4=0;g4<4;g4++){
        float4 lv = *(float4*)&l_buf[qh*32 + g4*8 + hi*4];
        float rl[4] = {ga/lv.x, ga/lv.y, ga/lv.z, ga/lv.w};
        #pragma unroll
        for(int dt=0;dt<2;dt++){
          int e = h*HD + dt*32 + l31;
          #pragma unroll
          for(int j=0;j<4;j++){
            int r = g4*4 + j;
            int qrow = q0b + qh*64 + qg*32 + j + g4*8 + hi*4;
            float o = oacc[qg][dt][r]*rl[j] + bf2f(CT[qrow*E_DIM + e]);
            fusedT[qrow*E_DIM + swz64(e, qrow)] = f2bf(o);   // pre-swizzled
          }
        }
      }
    }
  }
  #undef STAGE
}

// ---- final: out(c,s) = gelu(rbn(rs_w . fused + rs_b)) fp32, 64x64 tiles ----
// DMA-staged from pre-swizzled Wrs / fusedT.
__global__ __launch_bounds__(256) void k_final(
    const unsigned short* __restrict__ Wrs,
    const unsigned short* __restrict__ fusedT,
    const float* __restrict__ rsb,
    const float* __restrict__ rw, const float* __restrict__ rbb,
    const float* __restrict__ rm, const float* __restrict__ rv,
    float* __restrict__ out){
  __shared__ unsigned short Als[64*64];
  __shared__ unsigned short Bls[64*64];
  int tid = threadIdx.x;
  int w = tid>>6, l = tid&63, g = l>>4, c16 = l&15;
  int wr2 = w>>1, wc2 = w&1;
  int sB0 = blockIdx.x*64, c0 = blockIdx.y*64;
  f4v acc[2][2];
  #pragma unroll
  for(int m=0;m<2;m++)
    #pragma unroll
    for(int n=0;n<2;n++) acc[m][n]=(f4v){0.f,0.f,0.f,0.f};
  for(int kk=0;kk<8;kk++){
    __syncthreads();
    #pragma unroll
    for(int p=0;p<2;p++){
      int flat = p*256+tid, row=flat>>3, ch=flat&7;
      gl_lds16(&Wrs[(c0+row)*E_DIM + kk*64 + ch*8], Als + (p*256 + w*64)*8);
    }
    #pragma unroll
    for(int p=0;p<2;p++){
      int flat = p*256+tid, row=flat>>3, ch=flat&7;
      gl_lds16(&fusedT[(sB0+row)*E_DIM + kk*64 + ch*8], Bls + (p*256 + w*64)*8);
    }
    asm volatile("s_waitcnt vmcnt(0)" ::: "memory");
    __syncthreads();
    #pragma unroll
    for(int kb=0;kb<2;kb++){
      s8v af[2]; s8v bfr[2];
      #pragma unroll
      for(int m=0;m<2;m++) af[m] = lds_rd8(Als, wr2*32 + m*16 + c16, g + kb*4);
      #pragma unroll
      for(int n=0;n<2;n++) bfr[n] = lds_rd8(Bls, wc2*32 + n*16 + c16, g + kb*4);
      #pragma unroll
      for(int m=0;m<2;m++)
        #pragma unroll
        for(int n=0;n<2;n++)
          acc[m][n] = __builtin_amdgcn_mfma_f32_16x16x32_bf16(af[m], bfr[n], acc[m][n],0,0,0);
    }
  }
  #pragma unroll
  for(int m=0;m<2;m++){
    #pragma unroll
    for(int i=0;i<4;i++){
      int c = c0 + wr2*32 + m*16 + g*4 + i;
      float bias = rsb[c];
      float rinv = rw[c]*rsqrtf(rv[c]+EPSV);
      float rbeta = rbb[c] - rm[c]*rinv;
      #pragma unroll
      for(int n=0;n<2;n++){
        int s = sB0 + wc2*32 + n*16 + c16;
        float vv = acc[m][n][i] + bias;
        vv = vv*rinv + rbeta;
        out[c*S_DIM + s] = 0.5f*vv*(1.0f + erff(vv*0.70710678118f));
      }
    }
  }
}

extern "C" void kernel_launch(void* const* d_in, const int* in_sizes, int n_in,
                              void* d_out, int out_size, void* d_ws, size_t ws_size,
                              hipStream_t stream){
  const float* x     = (const float*)d_in[0];
  const float* bn1w  = (const float*)d_in[1];
  const float* bn1b  = (const float*)d_in[2];
  const float* bn1m  = (const float*)d_in[3];
  const float* bn1v  = (const float*)d_in[4];
  const float* Wq    = (const float*)d_in[5];
  const float* bq    = (const float*)d_in[6];
  const float* Wk    = (const float*)d_in[7];
  const float* bk    = (const float*)d_in[8];
  const float* Wv    = (const float*)d_in[9];
  const float* bv    = (const float*)d_in[10];
  const float* gamma = (const float*)d_in[11];
  const float* temp  = (const float*)d_in[12];
  const float* convw = (const float*)d_in[13];
  const float* convb = (const float*)d_in[14];
  const float* cbnw  = (const float*)d_in[15];
  const float* cbnb  = (const float*)d_in[16];
  const float* cbnm  = (const float*)d_in[17];
  const float* cbnv  = (const float*)d_in[18];
  const float* rsw   = (const float*)d_in[19];
  const float* rsbp  = (const float*)d_in[20];
  const float* rbnw  = (const float*)d_in[21];
  const float* rbnb  = (const float*)d_in[22];
  const float* rbnm  = (const float*)d_in[23];
  const float* rbnv  = (const float*)d_in[24];
  float* out = (float*)d_out;

  unsigned short* ws  = (unsigned short*)d_ws;
  unsigned short* XaT = ws;                          // (S,C) bf16, pre-swizzled
  unsigned short* XrT = XaT + S_DIM*C_IN;            // (S,C) bf16, pre-swizzled
  unsigned short* Wb  = XrT + S_DIM*C_IN;            // weights bf16, pre-swizzled
  unsigned short* Wrs = Wb + 4*E_DIM*C_IN;           // rs weight bf16, pre-swizzled
  unsigned short* QT  = Wrs + C_IN*E_DIM;            // (S,E)
  unsigned short* KT  = QT + S_DIM*E_DIM;            // (S,E) chunk-swizzled
  unsigned short* Vx  = KT + S_DIM*E_DIM;            // (E,S) granule-swizzled
  unsigned short* CT  = Vx + S_DIM*E_DIM;            // (S,E) conv path
  unsigned short* fusedT = CT + S_DIM*E_DIM;         // (S,E) chunk-swizzled

  k_pre<<<dim3(3584),256,0,stream>>>(Wq, Wk, Wv, convw, rsw, Wb,
                                     x, bn1w, bn1b, bn1m, bn1v, XaT, XrT);
  k_proj<<<dim3(8,32,4),256,0,stream>>>(XaT, XrT, Wb, bq, bk, bv, convb,
                                        cbnw, cbnb, cbnm, cbnv, QT, KT, Vx, CT);
  k_attn<<<dim3(256),512,0,stream>>>(QT, KT, Vx, CT, gamma, temp, fusedT);
  k_final<<<dim3(64,4),256,0,stream>>>(Wrs, fusedT, rsbp, rbnw, rbnb, rbnm, rbnv, out);
}